// Round 1
// baseline (658.249 us; speedup 1.0000x reference)
//
#include <hip/hip_runtime.h>
#include <math.h>

// ---------------------------------------------------------------------------
// EncoderGPECls: kNN(16) -> PCA curvature blend -> adaptive GPE embeddings
// xyz: [8,4096,3] f32  ->  out: [8,4096,128] f32
//
// ws float layout:
//   [0, 32768)            curv per point
//   [32768, 131072)       rasig2 (3 SoA planes of 32768): 1/(0.3*(1+lstd_d)+1e-6)
//   [131072, 131080)      curv batch sums (atomic, zeroed via memsetAsync)
//   [131080, 131104)      per-(b,d) std (24)
//   [131104, 131108)      scalars: rasig1, blend, 1-blend
// ---------------------------------------------------------------------------

#define NPTS 4096
#define NB 8
#define KNN 17          // 16 neighbors + self (self contributes zero to sums)
#define CAP 4           // append-buffer depth before wave-synchronized compaction
#define BLKT 128

#define WS_CURV  0
#define WS_RAS2  32768
#define WS_CSUM  131072
#define WS_STD24 131080
#define WS_SCAL  131104

// ---------------- per-(b,d) std over N (ddof=1), double accumulation --------
__global__ void stats_kernel(const float* __restrict__ xyz, float* __restrict__ ws) {
    int b = blockIdx.x / 3, d = blockIdx.x % 3;
    const float* base = xyz + b * NPTS * 3 + d;
    double s = 0.0, ss = 0.0;
    for (int i = threadIdx.x; i < NPTS; i += 256) {
        double v = (double)base[i * 3];
        s += v; ss += v * v;
    }
    __shared__ double rs[256], rss[256];
    rs[threadIdx.x] = s; rss[threadIdx.x] = ss;
    __syncthreads();
    for (int off = 128; off > 0; off >>= 1) {
        if (threadIdx.x < off) {
            rs[threadIdx.x]  += rs[threadIdx.x + off];
            rss[threadIdx.x] += rss[threadIdx.x + off];
        }
        __syncthreads();
    }
    if (threadIdx.x == 0) {
        double var = (rss[0] - rs[0] * rs[0] / (double)NPTS) / (double)(NPTS - 1);
        ws[WS_STD24 + blockIdx.x] = (float)sqrt(var > 0.0 ? var : 0.0);
    }
}

// ---------------- gstd -> rasig1, blend ------------------------------------
__global__ void finalize_kernel(float* __restrict__ ws) {
    if (threadIdx.x == 0 && blockIdx.x == 0) {
        double g = 0.0;
        for (int i = 0; i < 24; i++) g += (double)ws[WS_STD24 + i];
        g *= (1.0 / 24.0);
        float gf = (float)g;
        float denom = 0.3f * (1.0f + gf) + 1e-6f;          // asig + EPS
        float blend = (float)(1.0 / (1.0 + exp(-((double)gf - 0.1) * 10.0)));
        ws[WS_SCAL + 0] = (float)(1.0 / (double)denom);
        ws[WS_SCAL + 1] = blend;
        ws[WS_SCAL + 2] = 1.0f - blend;                    // exact (Sterbenz)
    }
}

// ---------------- 3x3 symmetric eigensolve (double, trig method) -----------
__device__ __forceinline__ float curv_from_cov(float c00, float c01, float c02,
                                               float c11, float c12, float c22) {
    double a00 = c00, a01 = c01, a02 = c02, a11 = c11, a12 = c12, a22 = c22;
    double tr = a00 + a11 + a22;
    double q  = tr * (1.0 / 3.0);
    double b00 = a00 - q, b11 = a11 - q, b22 = a22 - q;
    double p2 = b00 * b00 + b11 * b11 + b22 * b22
              + 2.0 * (a01 * a01 + a02 * a02 + a12 * a12);
    double lmin;
    if (p2 < 1e-60) {
        lmin = q;
    } else {
        double p  = sqrt(p2 * (1.0 / 6.0));
        double ip = 1.0 / p;
        double m00 = b00 * ip, m11 = b11 * ip, m22 = b22 * ip;
        double m01 = a01 * ip, m02 = a02 * ip, m12 = a12 * ip;
        double det = m00 * (m11 * m22 - m12 * m12)
                   - m01 * (m01 * m22 - m12 * m02)
                   + m02 * (m01 * m12 - m11 * m02);
        double r = 0.5 * det;
        r = r > 1.0 ? 1.0 : (r < -1.0 ? -1.0 : r);
        double phi = acos(r) * (1.0 / 3.0);
        lmin = q + 2.0 * p * cos(phi + 2.0943951023931953); // +2pi/3 -> smallest
    }
    return (float)(lmin / (tr + 1e-6));
}

__device__ __forceinline__ void compact(float (&md)[KNN], int (&mi)[KNN],
                                        float (&bd)[CAP], int (&bi)[CAP],
                                        float& maxv, int& maxp, int& cnt) {
#pragma unroll
    for (int t = 0; t < CAP; t++) {
        bool ins = (t < cnt) && (bd[t] < maxv);
        if (ins) {
            float v = bd[t]; int ix = bi[t];
#pragma unroll
            for (int k = 0; k < KNN; k++) {
                bool s = (k == maxp);
                md[k] = s ? v  : md[k];
                mi[k] = s ? ix : mi[k];
            }
            maxv = md[0]; maxp = 0;
#pragma unroll
            for (int k = 1; k < KNN; k++) {
                bool gg = md[k] > maxv;
                maxv = gg ? md[k] : maxv;
                maxp = gg ? k : maxp;
            }
        }
    }
    cnt = 0;
}

// ---------------- kNN + covariance + curvature + lstd ----------------------
__global__ __launch_bounds__(BLKT) void knn_kernel(const float* __restrict__ xyz,
                                                   float* __restrict__ ws) {
    __shared__ float4 pts[NPTS];                 // 64 KB
    int b = blockIdx.x >> 5;                     // 32 blocks per batch
    int chunk = blockIdx.x & 31;
    const float* base = xyz + b * NPTS * 3;
    for (int p = threadIdx.x; p < NPTS; p += BLKT) {
        pts[p] = make_float4(base[p * 3], base[p * 3 + 1], base[p * 3 + 2], 0.0f);
    }
    __syncthreads();

    int i = chunk * BLKT + (int)threadIdx.x;     // this thread's query point
    float4 qp = pts[i];

    float md[KNN]; int mi[KNN];
#pragma unroll
    for (int k = 0; k < KNN; k++) { md[k] = 3.4e38f; mi[k] = 0; }
    float maxv = 3.4e38f; int maxp = 0;
    float bd[CAP]; int bi[CAP]; int cnt = 0;
#pragma unroll
    for (int k = 0; k < CAP; k++) { bd[k] = 0.0f; bi[k] = 0; }

    for (int j = 0; j < NPTS; j++) {
        float4 c = pts[j];
        float dx = qp.x - c.x, dy = qp.y - c.y, dz = qp.z - c.z;
        float d2 = dx * dx + dy * dy + dz * dz;  // self (j==i): exactly 0, kept
        bool app = d2 < maxv;
        if (app) {
#pragma unroll
            for (int k = 0; k < CAP; k++) {
                bool s = (k == cnt);
                bd[k] = s ? d2 : bd[k];
                bi[k] = s ? j  : bi[k];
            }
            cnt++;
        }
        if (__any(cnt == CAP)) {
            compact(md, mi, bd, bi, maxv, maxp, cnt);
        }
    }
    compact(md, mi, bd, bi, maxv, maxp, cnt);    // drain remainder

    // accumulate u = neigh - query over all 17 (self adds zero)
    float s1x = 0, s1y = 0, s1z = 0;
    float sxx = 0, sxy = 0, sxz = 0, syy = 0, syz = 0, szz = 0;
#pragma unroll
    for (int k = 0; k < KNN; k++) {
        float4 c = pts[mi[k]];
        float ux = c.x - qp.x, uy = c.y - qp.y, uz = c.z - qp.z;
        s1x += ux; s1y += uy; s1z += uz;
        sxx += ux * ux; sxy += ux * uy; sxz += ux * uz;
        syy += uy * uy; syz += uy * uz; szz += uz * uz;
    }
    const float i16 = 1.0f / 16.0f, i15 = 1.0f / 15.0f;
    float mx = s1x * i16, my = s1y * i16, mz = s1z * i16;
    float c00 = (sxx - 16.0f * mx * mx) * i15;
    float c01 = (sxy - 16.0f * mx * my) * i15;
    float c02 = (sxz - 16.0f * mx * mz) * i15;
    float c11 = (syy - 16.0f * my * my) * i15;
    float c12 = (syz - 16.0f * my * mz) * i15;
    float c22 = (szz - 16.0f * mz * mz) * i15;

    float curv = curv_from_cov(c00, c01, c02, c11, c12, c22);

    float v0 = c00 > 0.0f ? c00 : 0.0f;
    float v1 = c11 > 0.0f ? c11 : 0.0f;
    float v2 = c22 > 0.0f ? c22 : 0.0f;
    float r2x = 1.0f / (0.3f * (1.0f + sqrtf(v0)) + 1e-6f);
    float r2y = 1.0f / (0.3f * (1.0f + sqrtf(v1)) + 1e-6f);
    float r2z = 1.0f / (0.3f * (1.0f + sqrtf(v2)) + 1e-6f);

    int g = b * NPTS + i;
    ws[WS_CURV + g] = curv;
    ws[WS_RAS2 + 0 * 32768 + g] = r2x;
    ws[WS_RAS2 + 1 * 32768 + g] = r2y;
    ws[WS_RAS2 + 2 * 32768 + g] = r2z;

    // per-wave curv sum -> one atomic per wave per batch
    float cs = curv;
    for (int off = 32; off > 0; off >>= 1) cs += __shfl_down(cs, off);
    if ((threadIdx.x & 63) == 0) atomicAdd(&ws[WS_CSUM + b], cs);
}

// ---------------- final embedding ------------------------------------------
__global__ void out_kernel(const float* __restrict__ xyz,
                           const float* __restrict__ ws,
                           float* __restrict__ out) {
    int idx = blockIdx.x * 256 + (int)threadIdx.x;
    int j = idx & 127;
    int g = idx >> 7;
    int b = g >> 12;
    int f = (j < 127) ? j : 128;                      // OUT_IDX
    int d = (f >= 86) ? 2 : ((f >= 43) ? 1 : 0);
    int t = f - d * 43;
    float fv = (float)((double)(t + 1) * (2.0 / 44.0) - 1.0);  // FEAT_VAL[t]

    float x = xyz[g * 3 + d];
    float rasig1 = ws[WS_SCAL + 0];
    float blend  = ws[WS_SCAL + 1];
    float blendc = ws[WS_SCAL + 2];
    float cmean  = ws[WS_CSUM + b] * (1.0f / 4096.0f);
    float curv   = ws[WS_CURV + g];
    float w = 1.0f / (1.0f + __expf(-10.0f * (curv - cmean)));

    float t1 = (x - fv) * rasig1;
    float e1 = blend * __expf(-0.5f * t1 * t1) + blendc * __cosf(t1);
    float t2 = (x - fv) * ws[WS_RAS2 + (d << 15) + g];
    float e2 = __expf(-0.5f * t2 * t2);
    out[idx] = w * e1 + (1.0f - w) * e2;
}

extern "C" void kernel_launch(void* const* d_in, const int* in_sizes, int n_in,
                              void* d_out, int out_size, void* d_ws, size_t ws_size,
                              hipStream_t stream) {
    const float* xyz = (const float*)d_in[0];
    float* out = (float*)d_out;
    float* ws = (float*)d_ws;

    hipMemsetAsync(ws + WS_CSUM, 0, 8 * sizeof(float), stream);
    stats_kernel<<<24, 256, 0, stream>>>(xyz, ws);
    finalize_kernel<<<1, 64, 0, stream>>>(ws);
    knn_kernel<<<256, BLKT, 0, stream>>>(xyz, ws);
    out_kernel<<<out_size / 256, 256, 0, stream>>>(xyz, ws, out);
}

// Round 2
// 324.289 us; speedup vs baseline: 2.0298x; 2.0298x over previous
//
#include <hip/hip_runtime.h>
#include <math.h>

// ---------------------------------------------------------------------------
// EncoderGPECls: kNN(16) -> PCA curvature blend -> adaptive GPE embeddings
// xyz: [8,4096,3] f32  ->  out: [8,4096,128] f32
//
// R2: T=2 subset-split kNN (2 threads/query, shfl merge), 4-wide branch-free
//     candidate groups with prefetch, CAP=8 shift-register append buffer.
//
// ws float layout:
//   [0, 32768)            curv per point
//   [32768, 131072)       rasig2 (3 SoA planes of 32768): 1/(0.3*(1+lstd_d)+1e-6)
//   [131072, 131080)      curv batch sums (atomic, zeroed via memsetAsync)
//   [131080, 131104)      per-(b,d) std (24)
//   [131104, 131108)      scalars: rasig1, blend, 1-blend
// ---------------------------------------------------------------------------

#define NPTS 4096
#define NB 8
#define KNN 17          // 16 neighbors + self (self contributes zero to sums)
#define CAP 8           // shift-register append buffer depth
#define TSUB 2          // threads (subsets) per query
#define SUBN 2048       // NPTS / TSUB
#define BLKT 256        // 128 queries per block

#define WS_CURV  0
#define WS_RAS2  32768
#define WS_CSUM  131072
#define WS_STD24 131080
#define WS_SCAL  131104

// ---------------- per-(b,d) std over N (ddof=1), double accumulation --------
__global__ void stats_kernel(const float* __restrict__ xyz, float* __restrict__ ws) {
    int b = blockIdx.x / 3, d = blockIdx.x % 3;
    const float* base = xyz + b * NPTS * 3 + d;
    double s = 0.0, ss = 0.0;
    for (int i = threadIdx.x; i < NPTS; i += 256) {
        double v = (double)base[i * 3];
        s += v; ss += v * v;
    }
    __shared__ double rs[256], rss[256];
    rs[threadIdx.x] = s; rss[threadIdx.x] = ss;
    __syncthreads();
    for (int off = 128; off > 0; off >>= 1) {
        if (threadIdx.x < off) {
            rs[threadIdx.x]  += rs[threadIdx.x + off];
            rss[threadIdx.x] += rss[threadIdx.x + off];
        }
        __syncthreads();
    }
    if (threadIdx.x == 0) {
        double var = (rss[0] - rs[0] * rs[0] / (double)NPTS) / (double)(NPTS - 1);
        ws[WS_STD24 + blockIdx.x] = (float)sqrt(var > 0.0 ? var : 0.0);
    }
}

// ---------------- gstd -> rasig1, blend ------------------------------------
__global__ void finalize_kernel(float* __restrict__ ws) {
    if (threadIdx.x == 0 && blockIdx.x == 0) {
        double g = 0.0;
        for (int i = 0; i < 24; i++) g += (double)ws[WS_STD24 + i];
        g *= (1.0 / 24.0);
        float gf = (float)g;
        float denom = 0.3f * (1.0f + gf) + 1e-6f;          // asig + EPS
        float blend = (float)(1.0 / (1.0 + exp(-((double)gf - 0.1) * 10.0)));
        ws[WS_SCAL + 0] = (float)(1.0 / (double)denom);
        ws[WS_SCAL + 1] = blend;
        ws[WS_SCAL + 2] = 1.0f - blend;                    // exact (Sterbenz)
    }
}

// ---------------- 3x3 symmetric eigensolve (double, trig method) -----------
__device__ __forceinline__ float curv_from_cov(float c00, float c01, float c02,
                                               float c11, float c12, float c22) {
    double a00 = c00, a01 = c01, a02 = c02, a11 = c11, a12 = c12, a22 = c22;
    double tr = a00 + a11 + a22;
    double q  = tr * (1.0 / 3.0);
    double b00 = a00 - q, b11 = a11 - q, b22 = a22 - q;
    double p2 = b00 * b00 + b11 * b11 + b22 * b22
              + 2.0 * (a01 * a01 + a02 * a02 + a12 * a12);
    double lmin;
    if (p2 < 1e-60) {
        lmin = q;
    } else {
        double p  = sqrt(p2 * (1.0 / 6.0));
        double ip = 1.0 / p;
        double m00 = b00 * ip, m11 = b11 * ip, m22 = b22 * ip;
        double m01 = a01 * ip, m02 = a02 * ip, m12 = a12 * ip;
        double det = m00 * (m11 * m22 - m12 * m12)
                   - m01 * (m01 * m22 - m12 * m02)
                   + m02 * (m01 * m12 - m11 * m02);
        double r = 0.5 * det;
        r = r > 1.0 ? 1.0 : (r < -1.0 ? -1.0 : r);
        double phi = acos(r) * (1.0 / 3.0);
        lmin = q + 2.0 * p * cos(phi + 2.0943951023931953); // +2pi/3 -> smallest
    }
    return (float)(lmin / (tr + 1e-6));
}

// predicated replace-max insert into top-KNN (safe to run with ins=false)
__device__ __forceinline__ void insert1(float v, int ix, bool ins,
                                        float (&md)[KNN], int (&mi)[KNN],
                                        float& maxv, int& maxp) {
#pragma unroll
    for (int k = 0; k < KNN; k++) {
        bool sel = ins && (k == maxp);
        md[k] = sel ? v  : md[k];
        mi[k] = sel ? ix : mi[k];
    }
    maxv = md[0]; maxp = 0;
#pragma unroll
    for (int k = 1; k < KNN; k++) {
        bool gg = md[k] > maxv;
        maxv = gg ? md[k] : maxv;
        maxp = gg ? k : maxp;
    }
}

// drain append buffer (valid slots t < cnt, newest first; order irrelevant)
__device__ __forceinline__ void compact(float (&md)[KNN], int (&mi)[KNN],
                                        float (&bd)[CAP], int (&bi)[CAP],
                                        float& maxv, int& maxp, int& cnt) {
#pragma unroll
    for (int t = 0; t < CAP; t++) {
        bool ins = (t < cnt) && (bd[t] < maxv);
        if (__any(ins)) insert1(bd[t], bi[t], ins, md, mi, maxv, maxp);
    }
    cnt = 0;
}

// branchless predicated shift-register append
__device__ __forceinline__ void append1(float v, int j, bool p,
                                        float (&bd)[CAP], int (&bi)[CAP], int& cnt) {
#pragma unroll
    for (int t = CAP - 1; t > 0; t--) {
        bd[t] = p ? bd[t - 1] : bd[t];
        bi[t] = p ? bi[t - 1] : bi[t];
    }
    bd[0] = p ? v : bd[0];
    bi[0] = p ? j : bi[0];
    cnt += p ? 1 : 0;
}

// ---------------- kNN + covariance + curvature + lstd ----------------------
// T=2: lane 2q handles candidates [0,2048), lane 2q+1 handles [2048,4096),
// merged via shfl_xor(1); even lane computes/writes the per-point outputs.
__global__ __launch_bounds__(BLKT) void knn_kernel(const float* __restrict__ xyz,
                                                   float* __restrict__ ws) {
    __shared__ float4 pts[NPTS];                 // 64 KB
    int b = blockIdx.x >> 5;                     // 32 blocks per batch
    int chunk = blockIdx.x & 31;
    const float* base = xyz + b * NPTS * 3;
    for (int p = threadIdx.x; p < NPTS; p += BLKT) {
        pts[p] = make_float4(base[p * 3], base[p * 3 + 1], base[p * 3 + 2], 0.0f);
    }
    __syncthreads();

    int s = threadIdx.x & 1;                     // subset id
    int qlocal = threadIdx.x >> 1;               // 0..127
    int i = chunk * 128 + qlocal;                // query point index in batch
    float4 qp = pts[i];

    float md[KNN]; int mi[KNN];
#pragma unroll
    for (int k = 0; k < KNN; k++) { md[k] = 3.4e38f; mi[k] = 0; }
    float maxv = 3.4e38f; int maxp = 0;
    float bd[CAP]; int bi[CAP]; int cnt = 0;
#pragma unroll
    for (int k = 0; k < CAP; k++) { bd[k] = 0.0f; bi[k] = 0; }

    int jb = s * SUBN;
    float4 cc[4];
#pragma unroll
    for (int u = 0; u < 4; u++) cc[u] = pts[jb + u];

    for (int g = 0; g < SUBN; g += 4) {
        float4 cu[4];
#pragma unroll
        for (int u = 0; u < 4; u++) cu[u] = cc[u];
        int gn = (g + 4 < SUBN) ? (g + 4) : 0;   // clamp: last prefetch redundant
#pragma unroll
        for (int u = 0; u < 4; u++) cc[u] = pts[jb + gn + u];

        float d2v[4]; bool pr[4];
#pragma unroll
        for (int u = 0; u < 4; u++) {
            float dx = qp.x - cu[u].x, dy = qp.y - cu[u].y, dz = qp.z - cu[u].z;
            d2v[u] = dx * dx + dy * dy + dz * dz;   // self: exactly 0, kept
            pr[u] = d2v[u] < maxv;                  // stale maxv: conservative
        }
        if (__any(pr[0] | pr[1] | pr[2] | pr[3])) {
#pragma unroll
            for (int u = 0; u < 4; u++) append1(d2v[u], jb + g + u, pr[u], bd, bi, cnt);
        }
        if (__any(cnt > CAP - 4)) {              // room for next group's <=4
            compact(md, mi, bd, bi, maxv, maxp, cnt);
        }
    }
    compact(md, mi, bd, bi, maxv, maxp, cnt);    // drain remainder

    // merge partner's top-17 into even lane (odd lane's list stays pristine)
    bool receiver = (s == 0);
#pragma unroll
    for (int t = 0; t < KNN; t++) {
        float pv = __shfl_xor(md[t], 1);
        int   pi = __shfl_xor(mi[t], 1);
        bool ins = receiver && (pv < maxv);
        if (__any(ins)) insert1(pv, pi, ins, md, mi, maxv, maxp);
    }

    float curv = 0.0f;
    if (receiver) {
        // accumulate u = neigh - query over all 17 (self adds zero)
        float s1x = 0, s1y = 0, s1z = 0;
        float sxx = 0, sxy = 0, sxz = 0, syy = 0, syz = 0, szz = 0;
#pragma unroll
        for (int k = 0; k < KNN; k++) {
            float4 c = pts[mi[k]];
            float ux = c.x - qp.x, uy = c.y - qp.y, uz = c.z - qp.z;
            s1x += ux; s1y += uy; s1z += uz;
            sxx += ux * ux; sxy += ux * uy; sxz += ux * uz;
            syy += uy * uy; syz += uy * uz; szz += uz * uz;
        }
        const float i16 = 1.0f / 16.0f, i15 = 1.0f / 15.0f;
        float mx = s1x * i16, my = s1y * i16, mz = s1z * i16;
        float c00 = (sxx - 16.0f * mx * mx) * i15;
        float c01 = (sxy - 16.0f * mx * my) * i15;
        float c02 = (sxz - 16.0f * mx * mz) * i15;
        float c11 = (syy - 16.0f * my * my) * i15;
        float c12 = (syz - 16.0f * my * mz) * i15;
        float c22 = (szz - 16.0f * mz * mz) * i15;

        curv = curv_from_cov(c00, c01, c02, c11, c12, c22);

        float v0 = c00 > 0.0f ? c00 : 0.0f;
        float v1 = c11 > 0.0f ? c11 : 0.0f;
        float v2 = c22 > 0.0f ? c22 : 0.0f;
        float r2x = 1.0f / (0.3f * (1.0f + sqrtf(v0)) + 1e-6f);
        float r2y = 1.0f / (0.3f * (1.0f + sqrtf(v1)) + 1e-6f);
        float r2z = 1.0f / (0.3f * (1.0f + sqrtf(v2)) + 1e-6f);

        int g = b * NPTS + i;
        ws[WS_CURV + g] = curv;
        ws[WS_RAS2 + 0 * 32768 + g] = r2x;
        ws[WS_RAS2 + 1 * 32768 + g] = r2y;
        ws[WS_RAS2 + 2 * 32768 + g] = r2z;
    }

    // per-wave curv sum (odd lanes contribute 0) -> one atomic per wave
    float cs = curv;
    for (int off = 32; off > 0; off >>= 1) cs += __shfl_down(cs, off);
    if ((threadIdx.x & 63) == 0) atomicAdd(&ws[WS_CSUM + b], cs);
}

// ---------------- final embedding ------------------------------------------
__global__ void out_kernel(const float* __restrict__ xyz,
                           const float* __restrict__ ws,
                           float* __restrict__ out) {
    int idx = blockIdx.x * 256 + (int)threadIdx.x;
    int j = idx & 127;
    int g = idx >> 7;
    int b = g >> 12;
    int f = (j < 127) ? j : 128;                      // OUT_IDX
    int d = (f >= 86) ? 2 : ((f >= 43) ? 1 : 0);
    int t = f - d * 43;
    float fv = (float)((double)(t + 1) * (2.0 / 44.0) - 1.0);  // FEAT_VAL[t]

    float x = xyz[g * 3 + d];
    float rasig1 = ws[WS_SCAL + 0];
    float blend  = ws[WS_SCAL + 1];
    float blendc = ws[WS_SCAL + 2];
    float cmean  = ws[WS_CSUM + b] * (1.0f / 4096.0f);
    float curv   = ws[WS_CURV + g];
    float w = 1.0f / (1.0f + __expf(-10.0f * (curv - cmean)));

    float t1 = (x - fv) * rasig1;
    float e1 = blend * __expf(-0.5f * t1 * t1) + blendc * __cosf(t1);
    float t2 = (x - fv) * ws[WS_RAS2 + (d << 15) + g];
    float e2 = __expf(-0.5f * t2 * t2);
    out[idx] = w * e1 + (1.0f - w) * e2;
}

extern "C" void kernel_launch(void* const* d_in, const int* in_sizes, int n_in,
                              void* d_out, int out_size, void* d_ws, size_t ws_size,
                              hipStream_t stream) {
    const float* xyz = (const float*)d_in[0];
    float* out = (float*)d_out;
    float* ws = (float*)d_ws;

    hipMemsetAsync(ws + WS_CSUM, 0, 8 * sizeof(float), stream);
    stats_kernel<<<24, 256, 0, stream>>>(xyz, ws);
    finalize_kernel<<<1, 64, 0, stream>>>(ws);
    knn_kernel<<<256, BLKT, 0, stream>>>(xyz, ws);
    out_kernel<<<out_size / 256, 256, 0, stream>>>(xyz, ws, out);
}